// Round 8
// baseline (171.169 us; speedup 1.0000x reference)
//
#include <hip/hip_runtime.h>
#include <hip/hip_bf16.h>
#include <math.h>

typedef __bf16 bf16;
typedef bf16 bf16x8 __attribute__((ext_vector_type(8)));
typedef bf16 bf16x4 __attribute__((ext_vector_type(4)));
typedef float f32x4 __attribute__((ext_vector_type(4)));

#define N_NODES 8192
#define DIN 256
#define DOUT 256
#define KCAT 512
#define EPSF 1e-8f
#define KSPLIT 8
#define KBLK 1024          // K per k2 block
#define BM 128
#define BK 32
#define NT (KBLK / BK)     // 32 tiles
#define BUFSZ 24576        // A 8 KB + B 16 KB per stage
#define BBASE 8192         // B region offset within stage

__device__ __forceinline__ f32x4 mfma16(bf16x8 a, bf16x8 b, f32x4 c) {
    return __builtin_amdgcn_mfma_f32_16x16x32_bf16(a, b, c, 0, 0, 0);
}

#define WAITVM(N) asm volatile("s_waitcnt vmcnt(" #N ")" ::: "memory")
#define WAITLGKM  asm volatile("s_waitcnt lgkmcnt(0)" ::: "memory")
#define BAR       __builtin_amdgcn_s_barrier()

// ---------------- K0: W_w [256x256] -> WwT[n][k] bf16 ; W_fc [512x256] -> WfcT[n][k] bf16
__global__ __launch_bounds__(256) void k0_prep(const float* __restrict__ Ww,
                                               const float* __restrict__ Wfc,
                                               bf16* __restrict__ WwT,
                                               bf16* __restrict__ WfcT) {
    int tid = blockIdx.x * 256 + threadIdx.x;
    if (tid < 256 * 256) {
        int n = tid >> 8, k = tid & 255;
        WwT[n * 256 + k] = (bf16)Ww[k * 256 + n];
    }
    if (tid < 256 * 512) {
        int n = tid >> 9, k = tid & 511;
        WfcT[n * 512 + k] = (bf16)Wfc[k * 256 + n];
    }
}

// ---------------- K1: hT[col][m] = bf16(relu(X @ W_w + b_w))
__global__ __launch_bounds__(128) void k1_h(const float* __restrict__ X,
                                            const bf16* __restrict__ WwT,
                                            const float* __restrict__ bw,
                                            bf16* __restrict__ hT) {
    const int lane = threadIdx.x & 63;
    const int wid  = threadIdx.x >> 6;   // 0..1
    const int m0   = blockIdx.x * 16;
    const int lrow = lane & 15;
    const int lk8  = (lane >> 4) * 8;

    f32x4 acc[8];
#pragma unroll
    for (int i = 0; i < 8; ++i) acc[i] = {0.f, 0.f, 0.f, 0.f};

#pragma unroll
    for (int ks = 0; ks < DIN; ks += 32) {
        const float* xp = X + (size_t)(m0 + lrow) * DIN + ks + lk8;
        f32x4 x0 = *reinterpret_cast<const f32x4*>(xp);
        f32x4 x1 = *reinterpret_cast<const f32x4*>(xp + 4);
        bf16x8 a;
#pragma unroll
        for (int j = 0; j < 4; ++j) { a[j] = (bf16)x0[j]; a[4 + j] = (bf16)x1[j]; }
#pragma unroll
        for (int nb = 0; nb < 8; ++nb) {
            int col = wid * 128 + nb * 16 + lrow;
            bf16x8 b = *reinterpret_cast<const bf16x8*>(WwT + (size_t)col * DIN + ks + lk8);
            acc[nb] = mfma16(a, b, acc[nb]);
        }
    }
    const int mrow = m0 + (lane >> 4) * 4;
#pragma unroll
    for (int nb = 0; nb < 8; ++nb) {
        int col = wid * 128 + nb * 16 + lrow;
        float bias = bw[col];
        bf16x4 hv;
#pragma unroll
        for (int j = 0; j < 4; ++j) {
            float v = acc[nb][j] + bias;
            hv[j] = (bf16)(v > 0.f ? v : 0.f);
        }
        *reinterpret_cast<bf16x4*>(hT + (size_t)col * N_NODES + mrow) = hv;
    }
}

// ---------------- K2: part[ks] = A[m0:m0+128, kbase:+1024] @ h ; rsG[ks] = rowsum partial
// PHASE-DIVERSITY PROBE: per-CU work/traffic/reuse byte-identical to R3 (4096
// ds_read_b128, 8192 MFMA, same reads/MFMA=0.5, same A/hT bytes), but split as
// 2 co-resident blocks/CU (KSPLIT=8, KBLK=1024, BK=32, LDS 48 KB, <=128 VGPR
// via launch_bounds) -> two INDEPENDENT barrier chains per CU so one block's
// vmem wait hides under the other's compute (m114 mechanism).
// 8 waves as 2x4 of 64x64. Counted-vmcnt 2-stage dbuf (steady WAITVM(2)).
// Rowsum via fp32 VALU during staging (R7-verified) — no MFMA, no LDS scratch.
__global__ __launch_bounds__(512, 4) void k2_pool(const float* __restrict__ A,
                                                  const bf16* __restrict__ hT,
                                                  float* __restrict__ part,
                                                  float* __restrict__ rsG) {
    __shared__ __align__(16) unsigned char lds[2][BUFSZ];
    const int t    = threadIdx.x;
    const int lane = t & 63;
    const int wid  = t >> 6;        // 0..7
    const int wr   = wid >> 2;      // 0..1  (row half)
    const int wn   = wid & 3;       // 0..3  (col quarter)
    const int lrow = lane & 15;
    const int lk4  = lane >> 4;     // 0..3
    const int mblk = blockIdx.x & 63;
    const int ks   = blockIdx.x >> 6;   // 0..7
    const int m0   = mblk * BM;
    const int kbase = ks * KBLK;

    f32x4 acc[4][4];
#pragma unroll
    for (int i = 0; i < 4; ++i)
#pragma unroll
        for (int j = 0; j < 4; ++j) acc[i][j] = {0.f, 0.f, 0.f, 0.f};

    float rsum = 0.f;

    // ---- A staging: thread t -> row t>>2, seg t&3 (8 floats = 16 B bf16)
    const int arow = t >> 2;
    const int aseg = t & 3;
    const float* aSrc = A + (size_t)(m0 + arow) * N_NODES + kbase + aseg * 8;
    const int awb = arow * 64 + ((aseg ^ ((arow >> 1) & 3)) << 4);

    // ---- B DMA (2 rounds): idx=r*512+t -> col=idx>>2, phys seg=idx&3,
    //      global seg gs = (idx&3)^((col>>1)&3); LDS dest linear.
    const bf16* bsrc[2];
    int bdst[2];
#pragma unroll
    for (int r = 0; r < 2; ++r) {
        int idx = r * 512 + t;
        int col = idx >> 2;
        int gs  = (idx & 3) ^ ((col >> 1) & 3);
        bsrc[r] = hT + (size_t)col * N_NODES + kbase + gs * 8;
        bdst[r] = BBASE + r * 8192 + wid * 1024;   // + lane*16 applied by HW
    }

    // ---- fragment read byte offsets (BK=32 -> single k-slice, seg = lk4)
    int aOff[4], bOff[4];
#pragma unroll
    for (int mf = 0; mf < 4; ++mf) {
        int row = wr * 64 + mf * 16 + lrow;
        aOff[mf] = row * 64 + ((lk4 ^ ((row >> 1) & 3)) << 4);
    }
#pragma unroll
    for (int nf = 0; nf < 4; ++nf) {
        int col = wn * 64 + nf * 16 + lrow;
        bOff[nf] = BBASE + col * 64 + ((lk4 ^ ((col >> 1) & 3)) << 4);
    }

    f32x4 ra0, ra1;

#define ALOAD(tile) do {                                                      \
        const float* p_ = aSrc + (size_t)(tile) * BK;                         \
        ra0 = *reinterpret_cast<const f32x4*>(p_);                            \
        ra1 = *reinterpret_cast<const f32x4*>(p_ + 4);                        \
    } while (0)

#define CVTW(bufidx) do {                                                     \
        bf16x8 w_;                                                            \
        _Pragma("unroll")                                                     \
        for (int j_ = 0; j_ < 4; ++j_) {                                      \
            w_[j_]     = (bf16)ra0[j_];                                       \
            w_[4 + j_] = (bf16)ra1[j_];                                       \
            rsum += ra0[j_] + ra1[j_];                                        \
        }                                                                     \
        *reinterpret_cast<bf16x8*>(&lds[bufidx][awb]) = w_;                   \
    } while (0)

#define BDMA(tile, bufidx) do {                                               \
        _Pragma("unroll")                                                     \
        for (int r_ = 0; r_ < 2; ++r_) {                                      \
            __builtin_amdgcn_global_load_lds(                                 \
                (const __attribute__((address_space(1))) void*)(bsrc[r_] + (size_t)(tile) * BK), \
                (__attribute__((address_space(3))) void*)&lds[bufidx][bdst[r_]], \
                16, 0, 0);                                                    \
        }                                                                     \
    } while (0)

#define COMPUTE(bufidx) do {                                                  \
        bf16x8 af_[4], bf_[4];                                                \
        _Pragma("unroll")                                                     \
        for (int f = 0; f < 4; ++f) {                                         \
            af_[f] = *reinterpret_cast<const bf16x8*>(&lds[bufidx][aOff[f]]); \
            bf_[f] = *reinterpret_cast<const bf16x8*>(&lds[bufidx][bOff[f]]); \
        }                                                                     \
        _Pragma("unroll")                                                     \
        for (int mf = 0; mf < 4; ++mf)                                        \
            _Pragma("unroll")                                                 \
            for (int nf = 0; nf < 4; ++nf)                                    \
                acc[mf][nf] = mfma16(af_[mf], bf_[nf], acc[mf][nf]);          \
    } while (0)

    // ---------------- prologue
    ALOAD(0); BDMA(0, 0);
    CVTW(0);                     // compiler waits precisely on A(0)
    ALOAD(1); BDMA(1, 1);
    WAITVM(4);                   // retire B(0); leave A(1)+B(1) in flight
    WAITLGKM;
    BAR;                         // tile 0 ready

    // ---------------- main loop: tiles 0 .. NT-3
    for (int tt = 0; tt < NT - 2; ++tt) {
        CVTW((tt + 1) & 1);      // compiler waits A(tt+1) precisely (vmcnt 2)
        COMPUTE(tt & 1);
        ALOAD(tt + 2);
        WAITVM(2);               // retire B(tt+1); A(tt+2) stays in flight
        WAITLGKM;
        BAR;                     // tile tt+1 ready; buf tt&1 free
        BDMA(tt + 2, tt & 1);
    }
    // ---------------- tail: tiles NT-2, NT-1
    CVTW((NT - 1) & 1);
    COMPUTE((NT - 2) & 1);
    WAITVM(0);
    WAITLGKM;
    BAR;
    COMPUTE((NT - 1) & 1);

    // ---------------- rowsum: reduce 4 seg-partials per row (lanes t, t^1, t^2)
    rsum += __shfl_xor(rsum, 1);
    rsum += __shfl_xor(rsum, 2);
    if ((t & 3) == 0) rsG[(size_t)ks * N_NODES + m0 + arow] = rsum;

    // ---------------- store f32 partial tile
    float* pp = part + ((size_t)ks * N_NODES + m0) * DOUT;
#pragma unroll
    for (int mf = 0; mf < 4; ++mf)
#pragma unroll
        for (int nf = 0; nf < 4; ++nf) {
            int col = wn * 64 + nf * 16 + lrow;
#pragma unroll
            for (int j = 0; j < 4; ++j) {
                int row = wr * 64 + mf * 16 + lk4 * 4 + j;
                pp[(size_t)row * DOUT + col] = acc[mf][nf][j];
            }
        }
#undef ALOAD
#undef CVTW
#undef BDMA
#undef COMPUTE
}

// ---------------- K3: out = relu([X || pooled] @ W_fc + b_fc) + eps  (pooled formed
// on the fly from part/rsG — k2b merged in), + per-block sumsq partial
__global__ __launch_bounds__(128) void k3_out(const float* __restrict__ X,
                                              const float* __restrict__ part,
                                              const float* __restrict__ rsG,
                                              const bf16* __restrict__ WfcT,
                                              const float* __restrict__ bfc,
                                              float* __restrict__ out,
                                              float* __restrict__ partials) {
    const int lane = threadIdx.x & 63;
    const int wid  = threadIdx.x >> 6;
    const int m0   = blockIdx.x * 16;
    const int lrow = lane & 15;
    const int lk8  = (lane >> 4) * 8;

    f32x4 acc[8];
#pragma unroll
    for (int i = 0; i < 8; ++i) acc[i] = {0.f, 0.f, 0.f, 0.f};

    // per-lane row scale 1/(rowsum+eps) for row m0+lrow
    float rs = EPSF;
#pragma unroll
    for (int sp = 0; sp < KSPLIT; ++sp) rs += rsG[(size_t)sp * N_NODES + m0 + lrow];
    const float inv = 1.f / rs;

    // k in [0,256): A-operand from X (fp32 -> bf16)
#pragma unroll
    for (int ksx = 0; ksx < 256; ksx += 32) {
        const float* xp = X + (size_t)(m0 + lrow) * DIN + ksx + lk8;
        f32x4 x0 = *reinterpret_cast<const f32x4*>(xp);
        f32x4 x1 = *reinterpret_cast<const f32x4*>(xp + 4);
        bf16x8 a;
#pragma unroll
        for (int j = 0; j < 4; ++j) { a[j] = (bf16)x0[j]; a[4 + j] = (bf16)x1[j]; }
#pragma unroll
        for (int nb = 0; nb < 8; ++nb) {
            int col = wid * 128 + nb * 16 + lrow;
            bf16x8 b = *reinterpret_cast<const bf16x8*>(WfcT + (size_t)col * KCAT + ksx + lk8);
            acc[nb] = mfma16(a, b, acc[nb]);
        }
    }
    // k in [256,512): A-operand = pooled, formed from sum of part splits * inv
#pragma unroll
    for (int ksx = 256; ksx < 512; ksx += 32) {
        f32x4 s0 = {0.f, 0.f, 0.f, 0.f}, s1 = {0.f, 0.f, 0.f, 0.f};
#pragma unroll
        for (int sp = 0; sp < KSPLIT; ++sp) {
            const float* pp = part + ((size_t)sp * N_NODES + m0 + lrow) * DOUT + (ksx - 256) + lk8;
            f32x4 v0 = *reinterpret_cast<const f32x4*>(pp);
            f32x4 v1 = *reinterpret_cast<const f32x4*>(pp + 4);
#pragma unroll
            for (int j = 0; j < 4; ++j) { s0[j] += v0[j]; s1[j] += v1[j]; }
        }
        bf16x8 a;
#pragma unroll
        for (int j = 0; j < 4; ++j) { a[j] = (bf16)(s0[j] * inv); a[4 + j] = (bf16)(s1[j] * inv); }
#pragma unroll
        for (int nb = 0; nb < 8; ++nb) {
            int col = wid * 128 + nb * 16 + lrow;
            bf16x8 b = *reinterpret_cast<const bf16x8*>(WfcT + (size_t)col * KCAT + ksx + lk8);
            acc[nb] = mfma16(a, b, acc[nb]);
        }
    }

    float ss = 0.f;
#pragma unroll
    for (int nb = 0; nb < 8; ++nb) {
        int col = wid * 128 + nb * 16 + lrow;
        float bias = bfc[col];
#pragma unroll
        for (int j = 0; j < 4; ++j) {
            int row = m0 + (lane >> 4) * 4 + j;
            float v = acc[nb][j] + bias;
            v = (v > 0.f ? v : 0.f) + EPSF;
            out[(size_t)row * DOUT + col] = v;
            ss += v * v;
        }
    }
#pragma unroll
    for (int off = 32; off; off >>= 1) ss += __shfl_xor(ss, off);
    __shared__ float sw[2];
    if (lane == 0) sw[wid] = ss;
    __syncthreads();
    if (threadIdx.x == 0) partials[blockIdx.x] = sw[0] + sw[1];
}

// ---------------- K4: deterministic reduce of 512 partials; scale out by 1/(norm+eps)
__global__ __launch_bounds__(256) void k4_norm(float* __restrict__ out,
                                               const float* __restrict__ partials) {
    __shared__ float sw[4];
    float s = partials[threadIdx.x] + partials[threadIdx.x + 256];
#pragma unroll
    for (int off = 32; off; off >>= 1) s += __shfl_xor(s, off);
    if ((threadIdx.x & 63) == 0) sw[threadIdx.x >> 6] = s;
    __syncthreads();
    float total = sw[0] + sw[1] + sw[2] + sw[3];
    float scale = 1.f / (sqrtf(total) + EPSF);
    f32x4* o4 = reinterpret_cast<f32x4*>(out);
    const int nvec = N_NODES * DOUT / 4;
    for (int i = blockIdx.x * blockDim.x + threadIdx.x; i < nvec; i += gridDim.x * blockDim.x) {
        f32x4 v = o4[i];
#pragma unroll
        for (int j = 0; j < 4; ++j) v[j] *= scale;
        o4[i] = v;
    }
}

extern "C" void kernel_launch(void* const* d_in, const int* in_sizes, int n_in,
                              void* d_out, int out_size, void* d_ws, size_t ws_size,
                              hipStream_t stream) {
    const float* A   = (const float*)d_in[0];
    const float* X   = (const float*)d_in[1];
    const float* Ww  = (const float*)d_in[2];
    const float* bw  = (const float*)d_in[3];
    const float* Wfc = (const float*)d_in[4];
    const float* bfc = (const float*)d_in[5];
    float* out = (float*)d_out;

    char* ws = (char*)d_ws;
    bf16*  hT        = (bf16*)(ws);                                  // 4 MiB
    bf16*  WwT       = (bf16*)(ws + (8u << 20));                     // 128 KiB
    bf16*  WfcT      = (bf16*)(ws + (8u << 20) + (128u << 10));      // 256 KiB
    float* partials  = (float*)(ws + (8u << 20) + (384u << 10));     // 2 KiB
    float* rsG       = (float*)(ws + (8u << 20) + (512u << 10));     // 256 KiB (8 splits)
    float* part      = (float*)(ws + (16u << 20));                   // 64 MiB (8 splits)

    k0_prep<<<512, 256, 0, stream>>>(Ww, Wfc, WwT, WfcT);
    k1_h<<<512, 128, 0, stream>>>(X, WwT, bw, hT);
    k2_pool<<<512, 512, 0, stream>>>(A, hT, part, rsG);
    k3_out<<<512, 128, 0, stream>>>(X, part, rsG, WfcT, bfc, out, partials);
    k4_norm<<<256, 256, 0, stream>>>(out, partials);
}

// Round 9
// 158.449 us; speedup vs baseline: 1.0803x; 1.0803x over previous
//
#include <hip/hip_runtime.h>
#include <hip/hip_bf16.h>
#include <math.h>

typedef __bf16 bf16;
typedef bf16 bf16x8 __attribute__((ext_vector_type(8)));
typedef bf16 bf16x4 __attribute__((ext_vector_type(4)));
typedef float f32x4 __attribute__((ext_vector_type(4)));

#define N_NODES 8192
#define DIN 256
#define DOUT 256
#define KCAT 512
#define EPSF 1e-8f
#define KSPLIT 8
#define KBLK 1024          // K per k2 block
#define BM 256
#define BK 64
#define NT (KBLK / BK)     // 16 tiles
#define BBASE 32768        // B region offset within stage (A: 256 rows x 128 B)
#define BUFSZ 65536        // A 32 KB + B 32 KB per stage

__device__ __forceinline__ f32x4 mfma16(bf16x8 a, bf16x8 b, f32x4 c) {
    return __builtin_amdgcn_mfma_f32_16x16x32_bf16(a, b, c, 0, 0, 0);
}

#define WAITVM(N) asm volatile("s_waitcnt vmcnt(" #N ")" ::: "memory")
#define WAITLGKM  asm volatile("s_waitcnt lgkmcnt(0)" ::: "memory")
#define BAR       __builtin_amdgcn_s_barrier()

// ---------------- K0: W_w [256x256] -> WwT[n][k] bf16 ; W_fc [512x256] -> WfcT[n][k] bf16
__global__ __launch_bounds__(256) void k0_prep(const float* __restrict__ Ww,
                                               const float* __restrict__ Wfc,
                                               bf16* __restrict__ WwT,
                                               bf16* __restrict__ WfcT) {
    int tid = blockIdx.x * 256 + threadIdx.x;
    if (tid < 256 * 256) {
        int n = tid >> 8, k = tid & 255;
        WwT[n * 256 + k] = (bf16)Ww[k * 256 + n];
    }
    if (tid < 256 * 512) {
        int n = tid >> 9, k = tid & 511;
        WfcT[n * 512 + k] = (bf16)Wfc[k * 256 + n];
    }
}

// ---------------- K1: hT[col][m] = bf16(relu(X @ W_w + b_w))
__global__ __launch_bounds__(128) void k1_h(const float* __restrict__ X,
                                            const bf16* __restrict__ WwT,
                                            const float* __restrict__ bw,
                                            bf16* __restrict__ hT) {
    const int lane = threadIdx.x & 63;
    const int wid  = threadIdx.x >> 6;   // 0..1
    const int m0   = blockIdx.x * 16;
    const int lrow = lane & 15;
    const int lk8  = (lane >> 4) * 8;

    f32x4 acc[8];
#pragma unroll
    for (int i = 0; i < 8; ++i) acc[i] = {0.f, 0.f, 0.f, 0.f};

#pragma unroll
    for (int ks = 0; ks < DIN; ks += 32) {
        const float* xp = X + (size_t)(m0 + lrow) * DIN + ks + lk8;
        f32x4 x0 = *reinterpret_cast<const f32x4*>(xp);
        f32x4 x1 = *reinterpret_cast<const f32x4*>(xp + 4);
        bf16x8 a;
#pragma unroll
        for (int j = 0; j < 4; ++j) { a[j] = (bf16)x0[j]; a[4 + j] = (bf16)x1[j]; }
#pragma unroll
        for (int nb = 0; nb < 8; ++nb) {
            int col = wid * 128 + nb * 16 + lrow;
            bf16x8 b = *reinterpret_cast<const bf16x8*>(WwT + (size_t)col * DIN + ks + lk8);
            acc[nb] = mfma16(a, b, acc[nb]);
        }
    }
    const int mrow = m0 + (lane >> 4) * 4;
#pragma unroll
    for (int nb = 0; nb < 8; ++nb) {
        int col = wid * 128 + nb * 16 + lrow;
        float bias = bw[col];
        bf16x4 hv;
#pragma unroll
        for (int j = 0; j < 4; ++j) {
            float v = acc[nb][j] + bias;
            hv[j] = (bf16)(v > 0.f ? v : 0.f);
        }
        *reinterpret_cast<bf16x4*>(hT + (size_t)col * N_NODES + mrow) = hv;
    }
}

// ---------------- K2: part[ks] = A[m0:m0+256, kbase:+1024] @ h ; rsG[ks] = rowsum partial
// BM=256 probe: NT=16 fat iterations (96 KB traffic/iter) instead of 32 thin ones;
// B (hT) traffic halves to 128 MB total (one read per 256-row block).
// grid 256 = 8 ks (XCD-pinned: ks = bid&7, so each XCD's L2 holds ONE 512 KB
// hT k-slice instead of thrashing all 4 MB under the A stream) x 32 mblk.
// 8 waves as 4x2 of 64x128. Counted-vmcnt 2-stage dbuf (R3 ladder, re-traced
// for 8 A-loads + 4 B-DMAs per tile: prologue WAITVM(12), steady WAITVM(8)).
// Swizzle identical family to R3: row pitch 128 B, phys_seg = seg ^ (row&7),
// B source-pre-swizzled for linear global_load_lds dest; kki=1 seg = kki=0 ^ 64.
// Rowsum via fp32 VALU during staging + pair shfl (no MFMA, no LDS scratch).
__global__ __launch_bounds__(512, 2) void k2_pool(const float* __restrict__ A,
                                                  const bf16* __restrict__ hT,
                                                  float* __restrict__ part,
                                                  float* __restrict__ rsG) {
    __shared__ __align__(16) unsigned char lds[2][BUFSZ];
    const int t    = threadIdx.x;
    const int lane = t & 63;
    const int wid  = t >> 6;        // 0..7
    const int wr   = wid >> 1;      // 0..3  (64-row quarter)
    const int wn   = wid & 1;       // 0..1  (128-col half)
    const int lrow = lane & 15;
    const int lk4  = lane >> 4;     // 0..3
    const int ks   = blockIdx.x & 7;    // XCD-pinned k-slice
    const int mblk = blockIdx.x >> 3;   // 0..31
    const int m0   = mblk * BM;
    const int kbase = ks * KBLK;

    f32x4 acc[4][8];
#pragma unroll
    for (int i = 0; i < 4; ++i)
#pragma unroll
        for (int j = 0; j < 8; ++j) acc[i][j] = {0.f, 0.f, 0.f, 0.f};

    float rsum = 0.f;

    // ---- A staging: thread t -> row t>>1, half t&1 (32 floats = 64 B bf16 = 4 segs)
    const int arow = t >> 1;
    const int ahalf = t & 1;
    const float* aSrc = A + (size_t)(m0 + arow) * N_NODES + kbase + ahalf * 32;
    int awb[4];
#pragma unroll
    for (int i = 0; i < 4; ++i)
        awb[i] = arow * 128 + (((ahalf * 4 + i) ^ (arow & 7)) << 4);

    // ---- B DMA (4 rounds): idx=r*512+t -> col=idx>>3, phys seg=idx&7,
    //      global seg gs = (idx&7)^(col&7); LDS dest linear [col][seg].
    const bf16* bsrc[4];
    int bdst[4];
#pragma unroll
    for (int r = 0; r < 4; ++r) {
        int idx = r * 512 + t;
        int col = idx >> 3;
        int gs  = (idx & 7) ^ (col & 7);
        bsrc[r] = hT + (size_t)col * N_NODES + kbase + gs * 8;
        bdst[r] = BBASE + r * 8192 + wid * 1024;   // + lane*16 applied by HW
    }

    // ---- fragment read byte offsets (kki=0; kki=1 = ^64 since lk4<4)
    int aOffs[4], bOffs[8];
#pragma unroll
    for (int mf = 0; mf < 4; ++mf) {
        int row = wr * 64 + mf * 16 + lrow;
        aOffs[mf] = row * 128 + ((lk4 ^ (row & 7)) << 4);
    }
#pragma unroll
    for (int nf = 0; nf < 8; ++nf) {
        int col = wn * 128 + nf * 16 + lrow;
        bOffs[nf] = BBASE + col * 128 + ((lk4 ^ (col & 7)) << 4);
    }

    f32x4 ra[8];

#define ALOAD(tile) do {                                                      \
        const float* p_ = aSrc + (size_t)(tile) * BK;                         \
        _Pragma("unroll")                                                     \
        for (int q_ = 0; q_ < 8; ++q_)                                        \
            ra[q_] = *reinterpret_cast<const f32x4*>(p_ + q_ * 4);            \
    } while (0)

#define CVTW(bufidx) do {                                                     \
        _Pragma("unroll")                                                     \
        for (int i_ = 0; i_ < 4; ++i_) {                                      \
            bf16x8 w_;                                                        \
            _Pragma("unroll")                                                 \
            for (int j_ = 0; j_ < 4; ++j_) {                                  \
                w_[j_]     = (bf16)ra[2 * i_][j_];                            \
                w_[4 + j_] = (bf16)ra[2 * i_ + 1][j_];                        \
                rsum += ra[2 * i_][j_] + ra[2 * i_ + 1][j_];                  \
            }                                                                 \
            *reinterpret_cast<bf16x8*>(&lds[bufidx][awb[i_]]) = w_;           \
        }                                                                     \
    } while (0)

#define BDMA(tile, bufidx) do {                                               \
        _Pragma("unroll")                                                     \
        for (int r_ = 0; r_ < 4; ++r_) {                                      \
            __builtin_amdgcn_global_load_lds(                                 \
                (const __attribute__((address_space(1))) void*)(bsrc[r_] + (size_t)(tile) * BK), \
                (__attribute__((address_space(3))) void*)&lds[bufidx][bdst[r_]], \
                16, 0, 0);                                                    \
        }                                                                     \
    } while (0)

#define COMPUTE(bufidx) do {                                                  \
        _Pragma("unroll")                                                     \
        for (int kki = 0; kki < 2; ++kki) {                                   \
            bf16x8 af_[4];                                                    \
            _Pragma("unroll")                                                 \
            for (int mf = 0; mf < 4; ++mf)                                    \
                af_[mf] = *reinterpret_cast<const bf16x8*>(                   \
                    &lds[bufidx][aOffs[mf] ^ (kki << 6)]);                    \
            _Pragma("unroll")                                                 \
            for (int nf = 0; nf < 8; ++nf) {                                  \
                bf16x8 bf_ = *reinterpret_cast<const bf16x8*>(                \
                    &lds[bufidx][bOffs[nf] ^ (kki << 6)]);                    \
                _Pragma("unroll")                                             \
                for (int mf = 0; mf < 4; ++mf)                                \
                    acc[mf][nf] = mfma16(af_[mf], bf_, acc[mf][nf]);          \
            }                                                                 \
        }                                                                     \
    } while (0)

    // ---------------- prologue
    ALOAD(0); BDMA(0, 0);
    CVTW(0);                     // compiler waits precisely on A(0)
    ALOAD(1); BDMA(1, 1);
    WAITVM(12);                  // retire B(0); A(1)[8]+B(1)[4] stay in flight
    WAITLGKM;
    BAR;                         // tile 0 ready

    // ---------------- main loop: tiles 0 .. NT-3
    for (int tt = 0; tt < NT - 2; ++tt) {
        CVTW((tt + 1) & 1);      // compiler waits A(tt+1) precisely
        COMPUTE(tt & 1);
        ALOAD(tt + 2);
        WAITVM(8);               // retire B(tt+1); A(tt+2)[8] stays in flight
        WAITLGKM;
        BAR;                     // tile tt+1 ready; buf tt&1 free
        BDMA(tt + 2, tt & 1);
    }
    // ---------------- tail: tiles NT-2, NT-1
    CVTW((NT - 1) & 1);
    COMPUTE((NT - 2) & 1);
    WAITVM(0);
    WAITLGKM;
    BAR;
    COMPUTE((NT - 1) & 1);

    // ---------------- rowsum: reduce the 2 half-partials per row
    rsum += __shfl_xor(rsum, 1);
    if (ahalf == 0) rsG[(size_t)ks * N_NODES + m0 + arow] = rsum;

    // ---------------- store f32 partial tile
    float* pp = part + ((size_t)ks * N_NODES + m0) * DOUT;
#pragma unroll
    for (int mf = 0; mf < 4; ++mf)
#pragma unroll
        for (int nf = 0; nf < 8; ++nf) {
            int col = wn * 128 + nf * 16 + lrow;
#pragma unroll
            for (int j = 0; j < 4; ++j) {
                int row = wr * 64 + mf * 16 + lk4 * 4 + j;
                pp[(size_t)row * DOUT + col] = acc[mf][nf][j];
            }
        }
#undef ALOAD
#undef CVTW
#undef BDMA
#undef COMPUTE
}

// ---------------- K3: out = relu([X || pooled] @ W_fc + b_fc) + eps  (pooled formed
// on the fly from part/rsG — k2b merged in), + per-block sumsq partial
__global__ __launch_bounds__(128) void k3_out(const float* __restrict__ X,
                                              const float* __restrict__ part,
                                              const float* __restrict__ rsG,
                                              const bf16* __restrict__ WfcT,
                                              const float* __restrict__ bfc,
                                              float* __restrict__ out,
                                              float* __restrict__ partials) {
    const int lane = threadIdx.x & 63;
    const int wid  = threadIdx.x >> 6;
    const int m0   = blockIdx.x * 16;
    const int lrow = lane & 15;
    const int lk8  = (lane >> 4) * 8;

    f32x4 acc[8];
#pragma unroll
    for (int i = 0; i < 8; ++i) acc[i] = {0.f, 0.f, 0.f, 0.f};

    // per-lane row scale 1/(rowsum+eps) for row m0+lrow
    float rs = EPSF;
#pragma unroll
    for (int sp = 0; sp < KSPLIT; ++sp) rs += rsG[(size_t)sp * N_NODES + m0 + lrow];
    const float inv = 1.f / rs;

    // k in [0,256): A-operand from X (fp32 -> bf16)
#pragma unroll
    for (int ksx = 0; ksx < 256; ksx += 32) {
        const float* xp = X + (size_t)(m0 + lrow) * DIN + ksx + lk8;
        f32x4 x0 = *reinterpret_cast<const f32x4*>(xp);
        f32x4 x1 = *reinterpret_cast<const f32x4*>(xp + 4);
        bf16x8 a;
#pragma unroll
        for (int j = 0; j < 4; ++j) { a[j] = (bf16)x0[j]; a[4 + j] = (bf16)x1[j]; }
#pragma unroll
        for (int nb = 0; nb < 8; ++nb) {
            int col = wid * 128 + nb * 16 + lrow;
            bf16x8 b = *reinterpret_cast<const bf16x8*>(WfcT + (size_t)col * KCAT + ksx + lk8);
            acc[nb] = mfma16(a, b, acc[nb]);
        }
    }
    // k in [256,512): A-operand = pooled, formed from sum of part splits * inv
#pragma unroll
    for (int ksx = 256; ksx < 512; ksx += 32) {
        f32x4 s0 = {0.f, 0.f, 0.f, 0.f}, s1 = {0.f, 0.f, 0.f, 0.f};
#pragma unroll
        for (int sp = 0; sp < KSPLIT; ++sp) {
            const float* pp = part + ((size_t)sp * N_NODES + m0 + lrow) * DOUT + (ksx - 256) + lk8;
            f32x4 v0 = *reinterpret_cast<const f32x4*>(pp);
            f32x4 v1 = *reinterpret_cast<const f32x4*>(pp + 4);
#pragma unroll
            for (int j = 0; j < 4; ++j) { s0[j] += v0[j]; s1[j] += v1[j]; }
        }
        bf16x8 a;
#pragma unroll
        for (int j = 0; j < 4; ++j) { a[j] = (bf16)(s0[j] * inv); a[4 + j] = (bf16)(s1[j] * inv); }
#pragma unroll
        for (int nb = 0; nb < 8; ++nb) {
            int col = wid * 128 + nb * 16 + lrow;
            bf16x8 b = *reinterpret_cast<const bf16x8*>(WfcT + (size_t)col * KCAT + ksx + lk8);
            acc[nb] = mfma16(a, b, acc[nb]);
        }
    }

    float ss = 0.f;
#pragma unroll
    for (int nb = 0; nb < 8; ++nb) {
        int col = wid * 128 + nb * 16 + lrow;
        float bias = bfc[col];
#pragma unroll
        for (int j = 0; j < 4; ++j) {
            int row = m0 + (lane >> 4) * 4 + j;
            float v = acc[nb][j] + bias;
            v = (v > 0.f ? v : 0.f) + EPSF;
            out[(size_t)row * DOUT + col] = v;
            ss += v * v;
        }
    }
#pragma unroll
    for (int off = 32; off; off >>= 1) ss += __shfl_xor(ss, off);
    __shared__ float sw[2];
    if (lane == 0) sw[wid] = ss;
    __syncthreads();
    if (threadIdx.x == 0) partials[blockIdx.x] = sw[0] + sw[1];
}

// ---------------- K4: deterministic reduce of 512 partials; scale out by 1/(norm+eps)
__global__ __launch_bounds__(256) void k4_norm(float* __restrict__ out,
                                               const float* __restrict__ partials) {
    __shared__ float sw[4];
    float s = partials[threadIdx.x] + partials[threadIdx.x + 256];
#pragma unroll
    for (int off = 32; off; off >>= 1) s += __shfl_xor(s, off);
    if ((threadIdx.x & 63) == 0) sw[threadIdx.x >> 6] = s;
    __syncthreads();
    float total = sw[0] + sw[1] + sw[2] + sw[3];
    float scale = 1.f / (sqrtf(total) + EPSF);
    f32x4* o4 = reinterpret_cast<f32x4*>(out);
    const int nvec = N_NODES * DOUT / 4;
    for (int i = blockIdx.x * blockDim.x + threadIdx.x; i < nvec; i += gridDim.x * blockDim.x) {
        f32x4 v = o4[i];
#pragma unroll
        for (int j = 0; j < 4; ++j) v[j] *= scale;
        o4[i] = v;
    }
}

extern "C" void kernel_launch(void* const* d_in, const int* in_sizes, int n_in,
                              void* d_out, int out_size, void* d_ws, size_t ws_size,
                              hipStream_t stream) {
    const float* A   = (const float*)d_in[0];
    const float* X   = (const float*)d_in[1];
    const float* Ww  = (const float*)d_in[2];
    const float* bw  = (const float*)d_in[3];
    const float* Wfc = (const float*)d_in[4];
    const float* bfc = (const float*)d_in[5];
    float* out = (float*)d_out;

    char* ws = (char*)d_ws;
    bf16*  hT        = (bf16*)(ws);                                  // 4 MiB
    bf16*  WwT       = (bf16*)(ws + (8u << 20));                     // 128 KiB
    bf16*  WfcT      = (bf16*)(ws + (8u << 20) + (128u << 10));      // 256 KiB
    float* partials  = (float*)(ws + (8u << 20) + (384u << 10));     // 2 KiB
    float* rsG       = (float*)(ws + (8u << 20) + (512u << 10));     // 256 KiB (8 splits)
    float* part      = (float*)(ws + (16u << 20));                   // 64 MiB (8 splits)

    k0_prep<<<512, 256, 0, stream>>>(Ww, Wfc, WwT, WfcT);
    k1_h<<<512, 128, 0, stream>>>(X, WwT, bw, hT);
    k2_pool<<<256, 512, 0, stream>>>(A, hT, part, rsG);
    k3_out<<<512, 128, 0, stream>>>(X, part, rsG, WfcT, bfc, out, partials);
    k4_norm<<<256, 256, 0, stream>>>(out, partials);
}